// Round 5
// baseline (1081.238 us; speedup 1.0000x reference)
//
#include <hip/hip_runtime.h>
#include <float.h>
#include <math.h>

#define NN 8192
#define DH 256
#define KNN 10
#define TSTEPS 10
#define EPSC 0.1f

// spatial grid for kNN
#define GRD 32
#define NCELL (GRD * GRD * GRD)      // 32768
#define GL 5.6f                       // grid covers [-GL, GL]^3 (seed-0 max |coord| ~3.8)
#define GS (2.0f * GL / (float)GRD)   // 0.35 cell size
#define GINV ((float)GRD / (2.0f * GL))

typedef short s8v __attribute__((ext_vector_type(8)));
typedef float f4v __attribute__((ext_vector_type(4)));

__device__ __forceinline__ float bf2f(unsigned short u) {
    union { unsigned u; float f; } c; c.u = ((unsigned)u) << 16; return c.f;
}
__device__ __forceinline__ unsigned short f2bf(float f) {
    union { float f; unsigned u; } c; c.f = f;
    unsigned r = c.u + 0x7FFF + ((c.u >> 16) & 1);
    return (unsigned short)(r >> 16);
}

// Top-10 state as NAMED SCALARS — VGPR-resident, no arrays -> no scratch.
// Rank-parallel insert; strict '<' keeps the earlier-seen candidate on ties.
#define DECL_TOP10 \
    float b0=FLT_MAX,b1=FLT_MAX,b2=FLT_MAX,b3=FLT_MAX,b4=FLT_MAX, \
          b5=FLT_MAX,b6=FLT_MAX,b7=FLT_MAX,b8=FLT_MAX,b9=FLT_MAX; \
    int   i0=-1,i1=-1,i2=-1,i3=-1,i4=-1,i5=-1,i6=-1,i7=-1,i8=-1,i9=-1;

#define INS10(dv, jv) do { \
    float _d = (dv); int _j = (jv); \
    bool c0=_d<b0, c1=_d<b1, c2=_d<b2, c3=_d<b3, c4=_d<b4; \
    bool c5=_d<b5, c6=_d<b6, c7=_d<b7, c8=_d<b8, c9=_d<b9; \
    b9 = c9 ? (c8 ? b8 : _d) : b9;  i9 = c9 ? (c8 ? i8 : _j) : i9; \
    b8 = c8 ? (c7 ? b7 : _d) : b8;  i8 = c8 ? (c7 ? i7 : _j) : i8; \
    b7 = c7 ? (c6 ? b6 : _d) : b7;  i7 = c7 ? (c6 ? i6 : _j) : i7; \
    b6 = c6 ? (c5 ? b5 : _d) : b6;  i6 = c6 ? (c5 ? i5 : _j) : i6; \
    b5 = c5 ? (c4 ? b4 : _d) : b5;  i5 = c5 ? (c4 ? i4 : _j) : i5; \
    b4 = c4 ? (c3 ? b3 : _d) : b4;  i4 = c4 ? (c3 ? i3 : _j) : i4; \
    b3 = c3 ? (c2 ? b2 : _d) : b3;  i3 = c3 ? (c2 ? i2 : _j) : i3; \
    b2 = c2 ? (c1 ? b1 : _d) : b2;  i2 = c2 ? (c1 ? i1 : _j) : i2; \
    b1 = c1 ? (c0 ? b0 : _d) : b1;  i1 = c1 ? (c0 ? i0 : _j) : i1; \
    b0 = c0 ? _d : b0;              i0 = c0 ? _j : i0; \
} while (0)

__device__ __forceinline__ int bin1(float x) {
    int c = (int)floorf((x + GL) * GINV);
    return min(max(c, 0), GRD - 1);
}

// ---------------- conv_ws [3][256][256] (k,n) -> bf16 Wt [3][n][k] ------------
__global__ void prep_wt(const float* __restrict__ W, unsigned short* __restrict__ Wt) {
    int e = blockIdx.x * 256 + threadIdx.x;
    int g = e >> 16; int rem = e & 65535;
    int n = rem >> 8; int k = rem & 255;
    Wt[e] = f2bf(W[g * 65536 + k * 256 + n]);
}

// ---------------- grid build --------------------------------------------------
__global__ void grid_zero(int* __restrict__ counts) {
    counts[blockIdx.x * 256 + threadIdx.x] = 0;
}

__global__ void grid_bin(const float* __restrict__ pos, int* __restrict__ counts,
                         int* __restrict__ cellof, int* __restrict__ slotof) {
    int j = blockIdx.x * 256 + threadIdx.x;
    float x = pos[j * 3], y = pos[j * 3 + 1], z = pos[j * 3 + 2];
    int cid = (bin1(z) * GRD + bin1(y)) * GRD + bin1(x);
    int s = atomicAdd(&counts[cid], 1);
    cellof[j] = cid; slotof[j] = s;
}

// exclusive prefix over 32768 counts -> starts[0..NCELL]
__global__ void grid_prefix(const int* __restrict__ counts, int* __restrict__ starts) {
    __shared__ int psum[256];
    int t = threadIdx.x;
    const int CPT = NCELL / 256;     // 128
    int base = t * CPT;
    int s = 0;
    for (int c = 0; c < CPT; c++) s += counts[base + c];
    int v = s;
    psum[t] = v;
    __syncthreads();
    for (int off = 1; off < 256; off <<= 1) {
        int u = (t >= off) ? psum[t - off] : 0;
        __syncthreads();
        v += u;
        psum[t] = v;
        __syncthreads();
    }
    int run = v - s;                 // exclusive
    for (int c = 0; c < CPT; c++) { starts[base + c] = run; run += counts[base + c]; }
    if (t == 255) starts[NCELL] = run;
}

__global__ void grid_scatter(const float* __restrict__ pos, const int* __restrict__ starts,
                             const int* __restrict__ cellof, const int* __restrict__ slotof,
                             float4* __restrict__ spos, int* __restrict__ sidx) {
    int j = blockIdx.x * 256 + threadIdx.x;
    float x = pos[j * 3], y = pos[j * 3 + 1], z = pos[j * 3 + 2];
    int dst = starts[cellof[j]] + slotof[j];
    float4 v; v.x = x; v.y = y; v.z = z; v.w = x * x + y * y + z * z;
    spos[dst] = v;
    sidx[dst] = j;
}

// ---------------- grid kNN: expanding shells, provable termination ------------
// 128 blocks x 64 threads; lane owns sorted point k (cell-sorted -> coherent waves)
__launch_bounds__(64)
__global__ void knn_grid(const float4* __restrict__ spos, const int* __restrict__ sidx,
                         const int* __restrict__ starts, int* __restrict__ nbr) {
    int k = blockIdx.x * 64 + threadIdx.x;
    float4 q = spos[k];
    int iorig = sidx[k];
    float sqi = q.w;
    int cx = bin1(q.x), cy = bin1(q.y), cz = bin1(q.z);

    DECL_TOP10;
    for (int rho = 0; rho < GRD; rho++) {
        for (int dz = -rho; dz <= rho; dz++) {
            int z_ = cz + dz;
            if (z_ < 0 || z_ >= GRD) continue;
            for (int dy = -rho; dy <= rho; dy++) {
                int y_ = cy + dy;
                if (y_ < 0 || y_ >= GRD) continue;
                bool face = (abs(dz) == rho) || (abs(dy) == rho);
                int step = (face || rho == 0) ? 1 : 2 * rho;   // interior rows: only dx = +/-rho
                for (int dx = -rho; dx <= rho; dx += step) {
                    int x_ = cx + dx;
                    if (x_ < 0 || x_ >= GRD) continue;
                    int cid = (z_ * GRD + y_) * GRD + x_;
                    int cs = starts[cid], ce = starts[cid + 1];
                    for (int t = cs; t < ce; t++) {
                        float4 c = spos[t];
                        int jj = sidx[t];
                        float m = c.x * q.x + c.y * q.y + c.z * q.z;
                        float d = (sqi + c.w) - 2.0f * m;
                        if (jj == iorig) d = FLT_MAX;
                        INS10(d, jj);
                    }
                }
            }
        }
        // all unscanned points are >= rho*GS away (cheb cell-distance > rho)
        float bnd = (float)rho * GS;
        if (b9 <= bnd * bnd) break;
    }
    int* np = nbr + iorig * KNN;
    np[0] = i0; np[1] = i1; np[2] = i2; np[3] = i3; np[4] = i4;
    np[5] = i5; np[6] = i6; np[7] = i7; np[8] = i8; np[9] = i9;
}

// ---------------- h = lm@emb_w + emb_b ; x = h@rw + rb ------------------------
__global__ void emb_kernel(const float* __restrict__ lm, const float* __restrict__ ew,
                           const float* __restrict__ eb, const float* __restrict__ rw,
                           const float* __restrict__ rb,
                           float* __restrict__ hdo, unsigned short* __restrict__ hbf,
                           float* __restrict__ xout) {
    __shared__ float s0[4], s1[4], s2[4];
    int i = blockIdx.x, d = threadIdx.x;
    float a0 = lm[i * 3], a1 = lm[i * 3 + 1], a2 = lm[i * 3 + 2];
    float h = eb[d] + a0 * ew[d] + a1 * ew[256 + d] + a2 * ew[512 + d];
    hdo[i * 256 + d] = h;
    hbf[i * 256 + d] = f2bf(h);
    float p0 = h * rw[d * 3], p1 = h * rw[d * 3 + 1], p2 = h * rw[d * 3 + 2];
    for (int off = 32; off; off >>= 1) {
        p0 += __shfl_down(p0, off, 64);
        p1 += __shfl_down(p1, off, 64);
        p2 += __shfl_down(p2, off, 64);
    }
    int lane = d & 63, wid = d >> 6;
    if (lane == 0) { s0[wid] = p0; s1[wid] = p1; s2[wid] = p2; }
    __syncthreads();
    if (d == 0) {
        xout[i * 3 + 0] = s0[0] + s0[1] + s0[2] + s0[3] + rb[0];
        xout[i * 3 + 1] = s1[0] + s1[1] + s1[2] + s1[3] + rb[1];
        xout[i * 3 + 2] = s2[0] + s2[1] + s2[2] + s2[3] + rb[2];
    }
}

// ---------------- hop-1: x1[i] = 0.1 * sum_{j in nbr(i)} hbf[j] ---------------
__global__ void agg_kernel(const unsigned short* __restrict__ src,
                           unsigned short* __restrict__ dst,
                           const int* __restrict__ nbr) {
    int tid = threadIdx.x;
    int wid = tid >> 6, lane = tid & 63;
    int node = blockIdx.x * 4 + wid;
    int d0 = lane * 4;
    float a0 = 0.f, a1 = 0.f, a2 = 0.f, a3 = 0.f;
    const int* nb = nbr + node * KNN;
    for (int q = 0; q < KNN; q++) {
        int j = nb[q];
        uint2 v = *(const uint2*)(src + j * 256 + d0);
        a0 += bf2f((unsigned short)(v.x & 0xffff));
        a1 += bf2f((unsigned short)(v.x >> 16));
        a2 += bf2f((unsigned short)(v.y & 0xffff));
        a3 += bf2f((unsigned short)(v.y >> 16));
    }
    uint2 o;
    o.x = (unsigned)f2bf(a0 * 0.1f) | ((unsigned)f2bf(a1 * 0.1f) << 16);
    o.y = (unsigned)f2bf(a2 * 0.1f) | ((unsigned)f2bf(a3 * 0.1f) << 16);
    *(uint2*)(dst + node * 256 + d0) = o;
}

// ------- fused: hop-2 gather (x2 tile in LDS) + GEMM + Euler + readout --------
__launch_bounds__(256)
__global__ void gemm_step(unsigned short* hbf,
                          const unsigned short* __restrict__ x1,
                          const int* __restrict__ nbr,
                          const unsigned short* __restrict__ Wt,
                          const float* __restrict__ cb,
                          const float* __restrict__ rw, const float* __restrict__ rb,
                          float* hdo, float* __restrict__ yout, float* yfin) {
    __shared__ __align__(16) short Al[32 * 72];
    __shared__ __align__(16) short Bl[256 * 72];
    __shared__ __align__(16) short X2[32 * 264];
    __shared__ float rwl[768];
    __shared__ float cbl[256];
    __shared__ float yred[2][2][4][4][3];

    int tid = threadIdx.x;
    int m0 = blockIdx.x * 32;
    for (int idx = tid; idx < 768; idx += 256) rwl[idx] = rw[idx];
    cbl[tid] = cb[tid];

    // ---- fused hop-2 aggregation: X2[row][:] = bf16(0.1 * sum x1[nbr[row]]) ----
    {
        int row = tid >> 3, cg = tid & 7;
        const int* nb = nbr + (m0 + row) * KNN;
        float a[32];
#pragma unroll
        for (int e = 0; e < 32; e++) a[e] = 0.f;
        for (int q = 0; q < KNN; q++) {
            int j = nb[q];
            const uint4* p = (const uint4*)(x1 + j * 256 + cg * 32);
#pragma unroll
            for (int u = 0; u < 4; u++) {
                uint4 v = p[u];
                unsigned w0 = v.x, w1 = v.y, w2 = v.z, w3 = v.w;
                a[u*8+0] += bf2f((unsigned short)(w0 & 0xffff));
                a[u*8+1] += bf2f((unsigned short)(w0 >> 16));
                a[u*8+2] += bf2f((unsigned short)(w1 & 0xffff));
                a[u*8+3] += bf2f((unsigned short)(w1 >> 16));
                a[u*8+4] += bf2f((unsigned short)(w2 & 0xffff));
                a[u*8+5] += bf2f((unsigned short)(w2 >> 16));
                a[u*8+6] += bf2f((unsigned short)(w3 & 0xffff));
                a[u*8+7] += bf2f((unsigned short)(w3 >> 16));
            }
        }
        unsigned short* xp = (unsigned short*)&X2[row * 264 + cg * 32];
#pragma unroll
        for (int u = 0; u < 4; u++) {
            uint2 o;
            o.x = (unsigned)f2bf(a[u*8+0]*0.1f) | ((unsigned)f2bf(a[u*8+1]*0.1f) << 16);
            o.y = (unsigned)f2bf(a[u*8+2]*0.1f) | ((unsigned)f2bf(a[u*8+3]*0.1f) << 16);
            uint2 o2;
            o2.x = (unsigned)f2bf(a[u*8+4]*0.1f) | ((unsigned)f2bf(a[u*8+5]*0.1f) << 16);
            o2.y = (unsigned)f2bf(a[u*8+6]*0.1f) | ((unsigned)f2bf(a[u*8+7]*0.1f) << 16);
            *(uint2*)(xp + u * 8) = o;
            *(uint2*)(xp + u * 8 + 4) = o2;
        }
    }

    f4v acc[8];
    for (int f = 0; f < 8; f++) acc[f] = (f4v){0.f, 0.f, 0.f, 0.f};

    int w = tid >> 6, lane = tid & 63;
    int rowgrp = w & 1, nhalf = w >> 1;
    int quad = lane >> 4, l15 = lane & 15;

    for (int kc = 0; kc < 12; kc++) {
        int kb = kc * 64;
        int klocal = kb & 255;
        if (kc < 8) {
            const unsigned short* asrc = (kb < 256) ? (const unsigned short*)hbf : x1;
            int row = tid >> 3, c8 = (tid & 7) * 8;
            uint4 v = *(const uint4*)(asrc + (m0 + row) * 256 + klocal + c8);
            *(uint4*)(&Al[row * 72 + c8]) = v;
        }
        {
            const unsigned short* bsrc = Wt + (kb >> 8) * 65536;
            int c8 = (tid & 7) * 8, rbase = tid >> 3;
            for (int r2 = 0; r2 < 8; r2++) {
                int n = r2 * 32 + rbase;
                uint4 v = *(const uint4*)(bsrc + n * 256 + klocal + c8);
                *(uint4*)(&Bl[n * 72 + c8]) = v;
            }
        }
        __syncthreads();
        for (int ks = 0; ks < 2; ks++) {
            s8v a;
            if (kc < 8)
                a = *(const s8v*)(&Al[(rowgrp * 16 + l15) * 72 + ks * 32 + quad * 8]);
            else
                a = *(const s8v*)(&X2[(rowgrp * 16 + l15) * 264 + klocal + ks * 32 + quad * 8]);
            for (int f = 0; f < 8; f++) {
                int n = nhalf * 128 + f * 16 + l15;
                s8v b = *(const s8v*)(&Bl[n * 72 + ks * 32 + quad * 8]);
                acc[f] = __builtin_amdgcn_mfma_f32_16x16x32_bf16(a, b, acc[f], 0, 0, 0);
            }
        }
        __syncthreads();
    }

    float py[4][3] = {};
    for (int f = 0; f < 8; f++) {
        int col = nhalf * 128 + f * 16 + l15;
        float cbv = cbl[col];
        float rw0 = rwl[col * 3], rw1 = rwl[col * 3 + 1], rw2 = rwl[col * 3 + 2];
        for (int r = 0; r < 4; r++) {
            int grow = m0 + rowgrp * 16 + quad * 4 + r;
            float cval = acc[f][r] + cbv;
            float hn = hdo[grow * 256 + col] + EPSC * tanhf(cval);
            hdo[grow * 256 + col] = hn;
            hbf[grow * 256 + col] = f2bf(hn);
            py[r][0] += hn * rw0; py[r][1] += hn * rw1; py[r][2] += hn * rw2;
        }
    }
    for (int off = 1; off < 16; off <<= 1)
        for (int r = 0; r < 4; r++)
            for (int j = 0; j < 3; j++)
                py[r][j] += __shfl_xor(py[r][j], off, 64);
    if (l15 == 0)
        for (int r = 0; r < 4; r++)
            for (int j = 0; j < 3; j++)
                yred[rowgrp][nhalf][quad][r][j] = py[r][j];
    __syncthreads();
    if (nhalf == 0 && l15 == 0) {
        for (int r = 0; r < 4; r++) {
            int grow = m0 + rowgrp * 16 + quad * 4 + r;
            for (int j = 0; j < 3; j++) {
                float yv = yred[rowgrp][0][quad][r][j] + yred[rowgrp][1][quad][r][j] + rb[j];
                yout[grow * 3 + j] = yv;
                if (yfin) yfin[grow * 3 + j] = yv;
            }
        }
    }
}

extern "C" void kernel_launch(void* const* d_in, const int* in_sizes, int n_in,
                              void* d_out, int out_size, void* d_ws, size_t ws_size,
                              hipStream_t stream) {
    const float* lm = (const float*)d_in[0];
    const float* ew = (const float*)d_in[1];
    const float* eb = (const float*)d_in[2];
    const float* rw = (const float*)d_in[3];
    const float* rb = (const float*)d_in[4];
    const float* cw = (const float*)d_in[5];
    const float* cb = (const float*)d_in[6];

    float* out = (float*)d_out;
    float* y_out = out;
    float* h_out = out + 24576;
    float* x_out = out + 24576 + 2097152;
    float* lp_out = x_out + 24576;

    char* ws = (char*)d_ws;
    int* nbr = (int*)ws;            ws += NN * KNN * sizeof(int);        // 328 KB
    int* counts = (int*)ws;         ws += NCELL * sizeof(int);           // 128 KB
    int* starts = (int*)ws;         ws += (NCELL + 1) * sizeof(int);     // 128 KB
    int* cellof = (int*)ws;         ws += NN * sizeof(int);              // 32 KB
    int* slotof = (int*)ws;         ws += NN * sizeof(int);              // 32 KB
    float4* spos = (float4*)ws;     ws += NN * sizeof(float4);           // 128 KB
    int* sidx = (int*)ws;           ws += NN * sizeof(int);              // 32 KB
    unsigned short* hbf = (unsigned short*)ws; ws += NN * DH * 2;        // 4 MB
    unsigned short* x1  = (unsigned short*)ws; ws += NN * DH * 2;        // 4 MB
    unsigned short* Wt  = (unsigned short*)ws; ws += 3 * DH * DH * 2;    // 384 KB

    grid_zero<<<NCELL / 256, 256, 0, stream>>>(counts);
    grid_bin<<<NN / 256, 256, 0, stream>>>(lm, counts, cellof, slotof);
    grid_prefix<<<1, 256, 0, stream>>>(counts, starts);
    grid_scatter<<<NN / 256, 256, 0, stream>>>(lm, starts, cellof, slotof, spos, sidx);
    knn_grid<<<NN / 64, 64, 0, stream>>>(spos, sidx, starts, nbr);
    prep_wt<<<768, 256, 0, stream>>>(cw, Wt);
    emb_kernel<<<NN, 256, 0, stream>>>(lm, ew, eb, rw, rb, h_out, hbf, x_out);
    for (int t = 0; t < TSTEPS; t++) {
        agg_kernel<<<NN / 4, 256, 0, stream>>>(hbf, x1, nbr);
        gemm_step<<<NN / 32, 256, 0, stream>>>(hbf, x1, nbr, Wt, cb, rw, rb, h_out,
                                               lp_out + t * 24576,
                                               (t == TSTEPS - 1) ? y_out : nullptr);
    }
}

// Round 8
// 585.572 us; speedup vs baseline: 1.8465x; 1.8465x over previous
//
#include <hip/hip_runtime.h>
#include <float.h>
#include <math.h>

#define NN 8192
#define DH 256
#define KNN 10
#define TSTEPS 10
#define EPSC 0.1f
#define NSEG 16
#define SEGSZ (NN / NSEG)   // 512

// spatial grid (for query ORDERING only — correctness independent of GL/GRD)
#define GRD 32
#define NCELL (GRD * GRD * GRD)
#define GL 5.6f
#define GINV ((float)GRD / (2.0f * GL))

typedef short s8v __attribute__((ext_vector_type(8)));
typedef float f4v __attribute__((ext_vector_type(4)));

__device__ __forceinline__ float bf2f(unsigned short u) {
    union { unsigned u; float f; } c; c.u = ((unsigned)u) << 16; return c.f;
}
__device__ __forceinline__ unsigned short f2bf(float f) {
    union { float f; unsigned u; } c; c.f = f;
    unsigned r = c.u + 0x7FFF + ((c.u >> 16) & 1);
    return (unsigned short)(r >> 16);
}
__device__ __forceinline__ int bin1(float x) {
    int c = (int)floorf((x + GL) * GINV);
    return min(max(c, 0), GRD - 1);
}

// Top-10 as NAMED SCALARS — VGPR-resident (R2/R3 lesson: arrays spill).
#define DECL_TOP10 \
    float b0=FLT_MAX,b1=FLT_MAX,b2=FLT_MAX,b3=FLT_MAX,b4=FLT_MAX, \
          b5=FLT_MAX,b6=FLT_MAX,b7=FLT_MAX,b8=FLT_MAX,b9=FLT_MAX; \
    int   i0=-1,i1=-1,i2=-1,i3=-1,i4=-1,i5=-1,i6=-1,i7=-1,i8=-1,i9=-1;

#define INS10(dv, jv) do { \
    float _d = (dv); int _j = (jv); \
    bool c0=_d<b0, c1=_d<b1, c2=_d<b2, c3=_d<b3, c4=_d<b4; \
    bool c5=_d<b5, c6=_d<b6, c7=_d<b7, c8=_d<b8, c9=_d<b9; \
    b9 = c9 ? (c8 ? b8 : _d) : b9;  i9 = c9 ? (c8 ? i8 : _j) : i9; \
    b8 = c8 ? (c7 ? b7 : _d) : b8;  i8 = c8 ? (c7 ? i7 : _j) : i8; \
    b7 = c7 ? (c6 ? b6 : _d) : b7;  i7 = c7 ? (c6 ? i6 : _j) : i7; \
    b6 = c6 ? (c5 ? b5 : _d) : b6;  i6 = c6 ? (c5 ? i5 : _j) : i6; \
    b5 = c5 ? (c4 ? b4 : _d) : b5;  i5 = c5 ? (c4 ? i4 : _j) : i5; \
    b4 = c4 ? (c3 ? b3 : _d) : b4;  i4 = c4 ? (c3 ? i3 : _j) : i4; \
    b3 = c3 ? (c2 ? b2 : _d) : b3;  i3 = c3 ? (c2 ? i2 : _j) : i3; \
    b2 = c2 ? (c1 ? b1 : _d) : b2;  i2 = c2 ? (c1 ? i1 : _j) : i2; \
    b1 = c1 ? (c0 ? b0 : _d) : b1;  i1 = c1 ? (c0 ? i0 : _j) : i1; \
    b0 = c0 ? _d : b0;              i0 = c0 ? _j : i0; \
} while (0)

// distance-only variant for the s9 seed (10 regs, no indices)
#define DECL_TOP10D \
    float t0=FLT_MAX,t1=FLT_MAX,t2=FLT_MAX,t3=FLT_MAX,t4=FLT_MAX, \
          t5=FLT_MAX,t6=FLT_MAX,t7=FLT_MAX,t8=FLT_MAX,t9=FLT_MAX;
#define INS10D(dv) do { \
    float _d = (dv); \
    bool c0=_d<t0, c1=_d<t1, c2=_d<t2, c3=_d<t3, c4=_d<t4; \
    bool c5=_d<t5, c6=_d<t6, c7=_d<t7, c8=_d<t8, c9=_d<t9; \
    t9 = c9 ? (c8 ? t8 : _d) : t9; \
    t8 = c8 ? (c7 ? t7 : _d) : t8; \
    t7 = c7 ? (c6 ? t6 : _d) : t7; \
    t6 = c6 ? (c5 ? t5 : _d) : t6; \
    t5 = c5 ? (c4 ? t4 : _d) : t5; \
    t4 = c4 ? (c3 ? t3 : _d) : t4; \
    t3 = c3 ? (c2 ? t2 : _d) : t3; \
    t2 = c2 ? (c1 ? t1 : _d) : t2; \
    t1 = c1 ? (c0 ? t0 : _d) : t1; \
    t0 = c0 ? _d : t0; \
} while (0)

// ---------------- conv_ws [3][256][256] (k,n) -> bf16 Wt [3][n][k] ------------
__global__ void prep_wt(const float* __restrict__ W, unsigned short* __restrict__ Wt) {
    int e = blockIdx.x * 256 + threadIdx.x;
    int g = e >> 16; int rem = e & 65535;
    int n = rem >> 8; int k = rem & 255;
    Wt[e] = f2bf(W[g * 65536 + k * 256 + n]);
}

// ---------------- pos4[j] = {x, y, z, |p|^2}  (ORIGINAL index order) ----------
__global__ void prep_pos(const float* __restrict__ pos, float4* __restrict__ pos4) {
    int j = blockIdx.x * 256 + threadIdx.x;
    float x = pos[j * 3], y = pos[j * 3 + 1], z = pos[j * 3 + 2];
    float4 v; v.x = x; v.y = y; v.z = z; v.w = x * x + y * y + z * z;
    pos4[j] = v;
}

// ---------------- grid build (R5-verified) ------------------------------------
__global__ void grid_zero(int* __restrict__ counts) {
    counts[blockIdx.x * 256 + threadIdx.x] = 0;
}
__global__ void grid_bin(const float* __restrict__ pos, int* __restrict__ counts,
                         int* __restrict__ cellof, int* __restrict__ slotof) {
    int j = blockIdx.x * 256 + threadIdx.x;
    float x = pos[j * 3], y = pos[j * 3 + 1], z = pos[j * 3 + 2];
    int cid = (bin1(z) * GRD + bin1(y)) * GRD + bin1(x);
    int s = atomicAdd(&counts[cid], 1);
    cellof[j] = cid; slotof[j] = s;
}
__global__ void grid_prefix(const int* __restrict__ counts, int* __restrict__ starts) {
    __shared__ int psum[256];
    int t = threadIdx.x;
    const int CPT = NCELL / 256;
    int base = t * CPT;
    int s = 0;
    for (int c = 0; c < CPT; c++) s += counts[base + c];
    int v = s;
    psum[t] = v;
    __syncthreads();
    for (int off = 1; off < 256; off <<= 1) {
        int u = (t >= off) ? psum[t - off] : 0;
        __syncthreads();
        v += u;
        psum[t] = v;
        __syncthreads();
    }
    int run = v - s;
    for (int c = 0; c < CPT; c++) { starts[base + c] = run; run += counts[base + c]; }
    if (t == 255) starts[NCELL] = run;
}
__global__ void grid_scatter(const float* __restrict__ pos, const int* __restrict__ starts,
                             const int* __restrict__ cellof, const int* __restrict__ slotof,
                             float4* __restrict__ spos, int* __restrict__ sidx) {
    int j = blockIdx.x * 256 + threadIdx.x;
    float x = pos[j * 3], y = pos[j * 3 + 1], z = pos[j * 3 + 2];
    int dst = starts[cellof[j]] + slotof[j];
    float4 v; v.x = x; v.y = y; v.z = z; v.w = x * x + y * y + z * z;
    spos[dst] = v;
    sidx[dst] = j;
}

// ---------------- s9 seed: 10th-smallest distance within wave's 64-cluster ----
// s9[k] is an UPPER bound on query k's true 10-NN distance (10th of 63 others).
__launch_bounds__(64)
__global__ void s9_seed(const float4* __restrict__ spos, float* __restrict__ s9arr) {
    __shared__ float4 cl[64];
    int tid = threadIdx.x;
    int k = blockIdx.x * 64 + tid;
    float4 q = spos[k];
    cl[tid] = q;
    __syncthreads();
    DECL_TOP10D;
    for (int s = 0; s < 64; s++) {
        float4 c = cl[s];
        float m = c.x * q.x + c.y * q.y + c.z * q.z;
        float d = (q.w + c.w) - 2.0f * m;
        if (s == tid) d = FLT_MAX;
        INS10D(d);
    }
    s9arr[k] = t9;
}

// ---------------- kNN pass 1: guarded exact scan ------------------------------
// Queries in cell-sorted order (clustered waves); candidates in ORIGINAL order.
// Guard: wave-any(d <= s9). All true top-10 members pass (d <= r10 <= s9);
// unguarded-lane junk inserts are displaced => final set+tie-order EXACT.
__launch_bounds__(256)
__global__ void knn_scan(const float4* __restrict__ pos4, const float4* __restrict__ spos,
                         const int* __restrict__ sidx, const float* __restrict__ s9arr,
                         uint2* __restrict__ segdj) {
    __shared__ float4 cand[SEGSZ];
    int qb = blockIdx.x >> 4, seg = blockIdx.x & 15;
    int tid = threadIdx.x;
    int kq = qb * 256 + tid;
    for (int t = tid; t < SEGSZ; t += 256) cand[t] = pos4[seg * SEGSZ + t];
    float4 q = spos[kq];
    int iorig = sidx[kq];
    float s9 = s9arr[kq];
    __syncthreads();

    DECL_TOP10;
    int jbase = seg * SEGSZ;
#pragma unroll 4
    for (int t = 0; t < SEGSZ; t++) {
        float4 c = cand[t];
        float m = c.x * q.x + c.y * q.y + c.z * q.z;
        float d = (q.w + c.w) - 2.0f * m;
        int j = jbase + t;
        if (j == iorig) d = FLT_MAX;
        if (__any(d <= s9)) {          // wave-uniform branch; ~2-5% taken
            INS10(d, j);
        }
    }
    uint2* op = segdj + (seg * NN + kq) * KNN;
    op[0] = make_uint2(__float_as_uint(b0), (unsigned)i0);
    op[1] = make_uint2(__float_as_uint(b1), (unsigned)i1);
    op[2] = make_uint2(__float_as_uint(b2), (unsigned)i2);
    op[3] = make_uint2(__float_as_uint(b3), (unsigned)i3);
    op[4] = make_uint2(__float_as_uint(b4), (unsigned)i4);
    op[5] = make_uint2(__float_as_uint(b5), (unsigned)i5);
    op[6] = make_uint2(__float_as_uint(b6), (unsigned)i6);
    op[7] = make_uint2(__float_as_uint(b7), (unsigned)i7);
    op[8] = make_uint2(__float_as_uint(b8), (unsigned)i8);
    op[9] = make_uint2(__float_as_uint(b9), (unsigned)i9);
}

// ---------------- kNN pass 2: merge 16 lists (sorted-k indexed) ---------------
__global__ void knn_merge(const uint2* __restrict__ segdj, const int* __restrict__ sidx,
                          int* __restrict__ nbr) {
    int kq = blockIdx.x * 256 + threadIdx.x;
    DECL_TOP10;
    for (int s = 0; s < NSEG; s++) {       // ascending seg = ascending index on ties
        const uint2* p = segdj + (s * NN + kq) * KNN;
#pragma unroll
        for (int q = 0; q < KNN; q++) {
            uint2 v = p[q];
            INS10(__uint_as_float(v.x), (int)v.y);
        }
    }
    int* np = nbr + sidx[kq] * KNN;
    np[0] = i0; np[1] = i1; np[2] = i2; np[3] = i3; np[4] = i4;
    np[5] = i5; np[6] = i6; np[7] = i7; np[8] = i8; np[9] = i9;
}

// ---------------- h = lm@emb_w + emb_b ; x = h@rw + rb (R4 verbatim) ----------
__global__ void emb_kernel(const float* __restrict__ lm, const float* __restrict__ ew,
                           const float* __restrict__ eb, const float* __restrict__ rw,
                           const float* __restrict__ rb,
                           float* __restrict__ hdo, unsigned short* __restrict__ hbf,
                           float* __restrict__ xout) {
    __shared__ float s0[4], s1[4], s2[4];
    int i = blockIdx.x, d = threadIdx.x;
    float a0 = lm[i * 3], a1 = lm[i * 3 + 1], a2 = lm[i * 3 + 2];
    float h = eb[d] + a0 * ew[d] + a1 * ew[256 + d] + a2 * ew[512 + d];
    hdo[i * 256 + d] = h;
    hbf[i * 256 + d] = f2bf(h);
    float p0 = h * rw[d * 3], p1 = h * rw[d * 3 + 1], p2 = h * rw[d * 3 + 2];
    for (int off = 32; off; off >>= 1) {
        p0 += __shfl_down(p0, off, 64);
        p1 += __shfl_down(p1, off, 64);
        p2 += __shfl_down(p2, off, 64);
    }
    int lane = d & 63, wid = d >> 6;
    if (lane == 0) { s0[wid] = p0; s1[wid] = p1; s2[wid] = p2; }
    __syncthreads();
    if (d == 0) {
        xout[i * 3 + 0] = s0[0] + s0[1] + s0[2] + s0[3] + rb[0];
        xout[i * 3 + 1] = s1[0] + s1[1] + s1[2] + s1[3] + rb[1];
        xout[i * 3 + 2] = s2[0] + s2[1] + s2[2] + s2[3] + rb[2];
    }
}

// ---------------- hop-1 (R4 verbatim) -----------------------------------------
__global__ void agg_kernel(const unsigned short* __restrict__ src,
                           unsigned short* __restrict__ dst,
                           const int* __restrict__ nbr) {
    int tid = threadIdx.x;
    int wid = tid >> 6, lane = tid & 63;
    int node = blockIdx.x * 4 + wid;
    int d0 = lane * 4;
    float a0 = 0.f, a1 = 0.f, a2 = 0.f, a3 = 0.f;
    const int* nb = nbr + node * KNN;
    for (int q = 0; q < KNN; q++) {
        int j = nb[q];
        uint2 v = *(const uint2*)(src + j * 256 + d0);
        a0 += bf2f((unsigned short)(v.x & 0xffff));
        a1 += bf2f((unsigned short)(v.x >> 16));
        a2 += bf2f((unsigned short)(v.y & 0xffff));
        a3 += bf2f((unsigned short)(v.y >> 16));
    }
    uint2 o;
    o.x = (unsigned)f2bf(a0 * 0.1f) | ((unsigned)f2bf(a1 * 0.1f) << 16);
    o.y = (unsigned)f2bf(a2 * 0.1f) | ((unsigned)f2bf(a3 * 0.1f) << 16);
    *(uint2*)(dst + node * 256 + d0) = o;
}

// ------- fused hop-2 + GEMM + Euler + readout (R4 verbatim) -------------------
__launch_bounds__(256)
__global__ void gemm_step(unsigned short* hbf,
                          const unsigned short* __restrict__ x1,
                          const int* __restrict__ nbr,
                          const unsigned short* __restrict__ Wt,
                          const float* __restrict__ cb,
                          const float* __restrict__ rw, const float* __restrict__ rb,
                          float* hdo, float* __restrict__ yout, float* yfin) {
    __shared__ __align__(16) short Al[32 * 72];
    __shared__ __align__(16) short Bl[256 * 72];
    __shared__ __align__(16) short X2[32 * 264];
    __shared__ float rwl[768];
    __shared__ float cbl[256];
    __shared__ float yred[2][2][4][4][3];

    int tid = threadIdx.x;
    int m0 = blockIdx.x * 32;
    for (int idx = tid; idx < 768; idx += 256) rwl[idx] = rw[idx];
    cbl[tid] = cb[tid];

    {
        int row = tid >> 3, cg = tid & 7;
        const int* nb = nbr + (m0 + row) * KNN;
        float a[32];
#pragma unroll
        for (int e = 0; e < 32; e++) a[e] = 0.f;
        for (int q = 0; q < KNN; q++) {
            int j = nb[q];
            const uint4* p = (const uint4*)(x1 + j * 256 + cg * 32);
#pragma unroll
            for (int u = 0; u < 4; u++) {
                uint4 v = p[u];
                a[u*8+0] += bf2f((unsigned short)(v.x & 0xffff));
                a[u*8+1] += bf2f((unsigned short)(v.x >> 16));
                a[u*8+2] += bf2f((unsigned short)(v.y & 0xffff));
                a[u*8+3] += bf2f((unsigned short)(v.y >> 16));
                a[u*8+4] += bf2f((unsigned short)(v.z & 0xffff));
                a[u*8+5] += bf2f((unsigned short)(v.z >> 16));
                a[u*8+6] += bf2f((unsigned short)(v.w & 0xffff));
                a[u*8+7] += bf2f((unsigned short)(v.w >> 16));
            }
        }
        unsigned short* xp = (unsigned short*)&X2[row * 264 + cg * 32];
#pragma unroll
        for (int u = 0; u < 4; u++) {
            uint2 o;
            o.x = (unsigned)f2bf(a[u*8+0]*0.1f) | ((unsigned)f2bf(a[u*8+1]*0.1f) << 16);
            o.y = (unsigned)f2bf(a[u*8+2]*0.1f) | ((unsigned)f2bf(a[u*8+3]*0.1f) << 16);
            uint2 o2;
            o2.x = (unsigned)f2bf(a[u*8+4]*0.1f) | ((unsigned)f2bf(a[u*8+5]*0.1f) << 16);
            o2.y = (unsigned)f2bf(a[u*8+6]*0.1f) | ((unsigned)f2bf(a[u*8+7]*0.1f) << 16);
            *(uint2*)(xp + u * 8) = o;
            *(uint2*)(xp + u * 8 + 4) = o2;
        }
    }

    f4v acc[8];
    for (int f = 0; f < 8; f++) acc[f] = (f4v){0.f, 0.f, 0.f, 0.f};

    int w = tid >> 6, lane = tid & 63;
    int rowgrp = w & 1, nhalf = w >> 1;
    int quad = lane >> 4, l15 = lane & 15;

    for (int kc = 0; kc < 12; kc++) {
        int kb = kc * 64;
        int klocal = kb & 255;
        if (kc < 8) {
            const unsigned short* asrc = (kb < 256) ? hbf : x1;
            int row = tid >> 3, c8 = (tid & 7) * 8;
            uint4 v = *(const uint4*)(asrc + (m0 + row) * 256 + klocal + c8);
            *(uint4*)(&Al[row * 72 + c8]) = v;
        }
        {
            const unsigned short* bsrc = Wt + (kb >> 8) * 65536;
            int c8 = (tid & 7) * 8, rbase = tid >> 3;
            for (int r2 = 0; r2 < 8; r2++) {
                int n = r2 * 32 + rbase;
                uint4 v = *(const uint4*)(bsrc + n * 256 + klocal + c8);
                *(uint4*)(&Bl[n * 72 + c8]) = v;
            }
        }
        __syncthreads();
        for (int ks = 0; ks < 2; ks++) {
            s8v a;
            if (kc < 8)
                a = *(const s8v*)(&Al[(rowgrp * 16 + l15) * 72 + ks * 32 + quad * 8]);
            else
                a = *(const s8v*)(&X2[(rowgrp * 16 + l15) * 264 + klocal + ks * 32 + quad * 8]);
            for (int f = 0; f < 8; f++) {
                int n = nhalf * 128 + f * 16 + l15;
                s8v b = *(const s8v*)(&Bl[n * 72 + ks * 32 + quad * 8]);
                acc[f] = __builtin_amdgcn_mfma_f32_16x16x32_bf16(a, b, acc[f], 0, 0, 0);
            }
        }
        __syncthreads();
    }

    float py[4][3] = {};
    for (int f = 0; f < 8; f++) {
        int col = nhalf * 128 + f * 16 + l15;
        float cbv = cbl[col];
        float rw0 = rwl[col * 3], rw1 = rwl[col * 3 + 1], rw2 = rwl[col * 3 + 2];
        for (int r = 0; r < 4; r++) {
            int grow = m0 + rowgrp * 16 + quad * 4 + r;
            float cval = acc[f][r] + cbv;
            float hn = hdo[grow * 256 + col] + EPSC * tanhf(cval);
            hdo[grow * 256 + col] = hn;
            hbf[grow * 256 + col] = f2bf(hn);
            py[r][0] += hn * rw0; py[r][1] += hn * rw1; py[r][2] += hn * rw2;
        }
    }
    for (int off = 1; off < 16; off <<= 1)
        for (int r = 0; r < 4; r++)
            for (int j = 0; j < 3; j++)
                py[r][j] += __shfl_xor(py[r][j], off, 64);
    if (l15 == 0)
        for (int r = 0; r < 4; r++)
            for (int j = 0; j < 3; j++)
                yred[rowgrp][nhalf][quad][r][j] = py[r][j];
    __syncthreads();
    if (nhalf == 0 && l15 == 0) {
        for (int r = 0; r < 4; r++) {
            int grow = m0 + rowgrp * 16 + quad * 4 + r;
            for (int j = 0; j < 3; j++) {
                float yv = yred[rowgrp][0][quad][r][j] + yred[rowgrp][1][quad][r][j] + rb[j];
                yout[grow * 3 + j] = yv;
                if (yfin) yfin[grow * 3 + j] = yv;
            }
        }
    }
}

extern "C" void kernel_launch(void* const* d_in, const int* in_sizes, int n_in,
                              void* d_out, int out_size, void* d_ws, size_t ws_size,
                              hipStream_t stream) {
    const float* lm = (const float*)d_in[0];
    const float* ew = (const float*)d_in[1];
    const float* eb = (const float*)d_in[2];
    const float* rw = (const float*)d_in[3];
    const float* rb = (const float*)d_in[4];
    const float* cw = (const float*)d_in[5];
    const float* cb = (const float*)d_in[6];

    float* out = (float*)d_out;
    float* y_out = out;
    float* h_out = out + 24576;
    float* x_out = out + 24576 + 2097152;
    float* lp_out = x_out + 24576;

    char* ws = (char*)d_ws;
    int* nbr = (int*)ws;            ws += NN * KNN * sizeof(int);        // 328 KB
    float4* pos4 = (float4*)ws;     ws += NN * sizeof(float4);           // 128 KB
    int* counts = (int*)ws;         ws += NCELL * sizeof(int);           // 128 KB
    int* starts = (int*)ws;         ws += (NCELL + 1) * sizeof(int);     // 128 KB
    int* cellof = (int*)ws;         ws += NN * sizeof(int);              // 32 KB
    int* slotof = (int*)ws;         ws += NN * sizeof(int);              // 32 KB
    float4* spos = (float4*)ws;     ws += NN * sizeof(float4);           // 128 KB
    int* sidx = (int*)ws;           ws += NN * sizeof(int);              // 32 KB
    float* s9arr = (float*)ws;      ws += NN * sizeof(float);            // 32 KB
    // union: segdj (kNN scratch, 10.5 MB) aliases {hbf, x1, Wt} (sim, 8.4 MB)
    char* uni = ws;
    uint2* segdj = (uint2*)uni;
    unsigned short* hbf = (unsigned short*)uni;
    unsigned short* x1  = hbf + NN * DH;
    unsigned short* Wt  = x1 + NN * DH;

    prep_pos<<<NN / 256, 256, 0, stream>>>(lm, pos4);
    grid_zero<<<NCELL / 256, 256, 0, stream>>>(counts);
    grid_bin<<<NN / 256, 256, 0, stream>>>(lm, counts, cellof, slotof);
    grid_prefix<<<1, 256, 0, stream>>>(counts, starts);
    grid_scatter<<<NN / 256, 256, 0, stream>>>(lm, starts, cellof, slotof, spos, sidx);
    s9_seed<<<NN / 64, 64, 0, stream>>>(spos, s9arr);
    knn_scan<<<32 * NSEG, 256, 0, stream>>>(pos4, spos, sidx, s9arr, segdj);
    knn_merge<<<NN / 256, 256, 0, stream>>>(segdj, sidx, nbr);
    prep_wt<<<768, 256, 0, stream>>>(cw, Wt);
    emb_kernel<<<NN, 256, 0, stream>>>(lm, ew, eb, rw, rb, h_out, hbf, x_out);
    for (int t = 0; t < TSTEPS; t++) {
        agg_kernel<<<NN / 4, 256, 0, stream>>>(hbf, x1, nbr);
        gemm_step<<<NN / 32, 256, 0, stream>>>(hbf, x1, nbr, Wt, cb, rw, rb, h_out,
                                               lp_out + t * 24576,
                                               (t == TSTEPS - 1) ? y_out : nullptr);
    }
}

// Round 9
// 577.829 us; speedup vs baseline: 1.8712x; 1.0134x over previous
//
#include <hip/hip_runtime.h>
#include <float.h>
#include <math.h>

#define NN 8192
#define DH 256
#define KNN 10
#define TSTEPS 10
#define EPSC 0.1f
#define NSEG 16
#define SEGSZ (NN / NSEG)   // 512

// spatial grid (query ORDERING only — s9 bound exact regardless of grid quality)
#define GRD 32
#define NCELL (GRD * GRD * GRD)
#define GL 5.6f
#define GINV ((float)GRD / (2.0f * GL))

typedef short s8v __attribute__((ext_vector_type(8)));
typedef float f4v __attribute__((ext_vector_type(4)));

__device__ __forceinline__ float bf2f(unsigned short u) {
    union { unsigned u; float f; } c; c.u = ((unsigned)u) << 16; return c.f;
}
__device__ __forceinline__ unsigned short f2bf(float f) {
    union { float f; unsigned u; } c; c.f = f;
    unsigned r = c.u + 0x7FFF + ((c.u >> 16) & 1);
    return (unsigned short)(r >> 16);
}
__device__ __forceinline__ int bin1(float x) {
    int c = (int)floorf((x + GL) * GINV);
    return min(max(c, 0), GRD - 1);
}
// Morton 3D: spread 5 bits to positions {0,3,6,9,12}
__device__ __forceinline__ unsigned spread5(unsigned x) {
    x &= 0x1F;
    x = (x | (x << 8)) & 0x100F;
    x = (x | (x << 4)) & 0x10C3;
    x = (x | (x << 2)) & 0x1249;
    return x;
}

// Top-10 as NAMED SCALARS — VGPR-resident (R2/R3 lesson: arrays spill).
#define DECL_TOP10 \
    float b0=FLT_MAX,b1=FLT_MAX,b2=FLT_MAX,b3=FLT_MAX,b4=FLT_MAX, \
          b5=FLT_MAX,b6=FLT_MAX,b7=FLT_MAX,b8=FLT_MAX,b9=FLT_MAX; \
    int   i0=-1,i1=-1,i2=-1,i3=-1,i4=-1,i5=-1,i6=-1,i7=-1,i8=-1,i9=-1;

#define INS10(dv, jv) do { \
    float _d = (dv); int _j = (jv); \
    bool c0=_d<b0, c1=_d<b1, c2=_d<b2, c3=_d<b3, c4=_d<b4; \
    bool c5=_d<b5, c6=_d<b6, c7=_d<b7, c8=_d<b8, c9=_d<b9; \
    b9 = c9 ? (c8 ? b8 : _d) : b9;  i9 = c9 ? (c8 ? i8 : _j) : i9; \
    b8 = c8 ? (c7 ? b7 : _d) : b8;  i8 = c8 ? (c7 ? i7 : _j) : i8; \
    b7 = c7 ? (c6 ? b6 : _d) : b7;  i7 = c7 ? (c6 ? i6 : _j) : i7; \
    b6 = c6 ? (c5 ? b5 : _d) : b6;  i6 = c6 ? (c5 ? i5 : _j) : i6; \
    b5 = c5 ? (c4 ? b4 : _d) : b5;  i5 = c5 ? (c4 ? i4 : _j) : i5; \
    b4 = c4 ? (c3 ? b3 : _d) : b4;  i4 = c4 ? (c3 ? i3 : _j) : i4; \
    b3 = c3 ? (c2 ? b2 : _d) : b3;  i3 = c3 ? (c2 ? i2 : _j) : i3; \
    b2 = c2 ? (c1 ? b1 : _d) : b2;  i2 = c2 ? (c1 ? i1 : _j) : i2; \
    b1 = c1 ? (c0 ? b0 : _d) : b1;  i1 = c1 ? (c0 ? i0 : _j) : i1; \
    b0 = c0 ? _d : b0;              i0 = c0 ? _j : i0; \
} while (0)

// distance-only variant for the s9 seed
#define DECL_TOP10D \
    float t0=FLT_MAX,t1=FLT_MAX,t2=FLT_MAX,t3=FLT_MAX,t4=FLT_MAX, \
          t5=FLT_MAX,t6=FLT_MAX,t7=FLT_MAX,t8=FLT_MAX,t9=FLT_MAX;
#define INS10D(dv) do { \
    float _d = (dv); \
    bool c0=_d<t0, c1=_d<t1, c2=_d<t2, c3=_d<t3, c4=_d<t4; \
    bool c5=_d<t5, c6=_d<t6, c7=_d<t7, c8=_d<t8, c9=_d<t9; \
    t9 = c9 ? (c8 ? t8 : _d) : t9; \
    t8 = c8 ? (c7 ? t7 : _d) : t8; \
    t7 = c7 ? (c6 ? t6 : _d) : t7; \
    t6 = c6 ? (c5 ? t5 : _d) : t6; \
    t5 = c5 ? (c4 ? t4 : _d) : t5; \
    t4 = c4 ? (c3 ? t3 : _d) : t4; \
    t3 = c3 ? (c2 ? t2 : _d) : t3; \
    t2 = c2 ? (c1 ? t1 : _d) : t2; \
    t1 = c1 ? (c0 ? t0 : _d) : t1; \
    t0 = c0 ? _d : t0; \
} while (0)

// ---------------- conv_ws [3][256][256] (k,n) -> bf16 Wt [3][n][k] ------------
__global__ void prep_wt(const float* __restrict__ W, unsigned short* __restrict__ Wt) {
    int e = blockIdx.x * 256 + threadIdx.x;
    int g = e >> 16; int rem = e & 65535;
    int n = rem >> 8; int k = rem & 255;
    Wt[e] = f2bf(W[g * 65536 + k * 256 + n]);
}

// ---------------- pos4[j] = {x, y, z, |p|^2}  (ORIGINAL index order) ----------
__global__ void prep_pos(const float* __restrict__ pos, float4* __restrict__ pos4) {
    int j = blockIdx.x * 256 + threadIdx.x;
    float x = pos[j * 3], y = pos[j * 3 + 1], z = pos[j * 3 + 2];
    float4 v; v.x = x; v.y = y; v.z = z; v.w = x * x + y * y + z * z;
    pos4[j] = v;
}

// ---------------- grid build (Morton cell ids for compact sorted clusters) ----
__global__ void grid_zero(int* __restrict__ counts) {
    counts[blockIdx.x * 256 + threadIdx.x] = 0;
}
__global__ void grid_bin(const float* __restrict__ pos, int* __restrict__ counts,
                         int* __restrict__ cellof, int* __restrict__ slotof) {
    int j = blockIdx.x * 256 + threadIdx.x;
    float x = pos[j * 3], y = pos[j * 3 + 1], z = pos[j * 3 + 2];
    int cid = (int)(spread5((unsigned)bin1(x)) | (spread5((unsigned)bin1(y)) << 1)
                  | (spread5((unsigned)bin1(z)) << 2));
    int s = atomicAdd(&counts[cid], 1);
    cellof[j] = cid; slotof[j] = s;
}
__global__ void grid_prefix(const int* __restrict__ counts, int* __restrict__ starts) {
    __shared__ int psum[256];
    int t = threadIdx.x;
    const int CPT = NCELL / 256;
    int base = t * CPT;
    int s = 0;
    for (int c = 0; c < CPT; c++) s += counts[base + c];
    int v = s;
    psum[t] = v;
    __syncthreads();
    for (int off = 1; off < 256; off <<= 1) {
        int u = (t >= off) ? psum[t - off] : 0;
        __syncthreads();
        v += u;
        psum[t] = v;
        __syncthreads();
    }
    int run = v - s;
    for (int c = 0; c < CPT; c++) { starts[base + c] = run; run += counts[base + c]; }
    if (t == 255) starts[NCELL] = run;
}
__global__ void grid_scatter(const float* __restrict__ pos, const int* __restrict__ starts,
                             const int* __restrict__ cellof, const int* __restrict__ slotof,
                             float4* __restrict__ spos, int* __restrict__ sidx) {
    int j = blockIdx.x * 256 + threadIdx.x;
    float x = pos[j * 3], y = pos[j * 3 + 1], z = pos[j * 3 + 2];
    int dst = starts[cellof[j]] + slotof[j];
    float4 v; v.x = x; v.y = y; v.z = z; v.w = x * x + y * y + z * z;
    spos[dst] = v;
    sidx[dst] = j;
}

// ---------------- s9 seed: 10th-smallest distance within wave's 64-cluster ----
__launch_bounds__(64)
__global__ void s9_seed(const float4* __restrict__ spos, float* __restrict__ s9arr) {
    __shared__ float4 cl[64];
    int tid = threadIdx.x;
    int k = blockIdx.x * 64 + tid;
    float4 q = spos[k];
    cl[tid] = q;
    __syncthreads();
    DECL_TOP10D;
    for (int s = 0; s < 64; s++) {
        float4 c = cl[s];
        float m = c.x * q.x + c.y * q.y + c.z * q.z;
        float d = (q.w + c.w) - 2.0f * m;
        if (s == tid) d = FLT_MAX;
        INS10D(d);
    }
    s9arr[k] = t9;
}

// ---------------- kNN pass 1: guarded exact scan, chunk-of-8 ILP --------------
// Queries Morton-cell-sorted (compact waves); candidates in ORIGINAL order.
// 8 distances hoisted branch-free (named scalars), then per-candidate
// wave-any guard. Exact: every true top-10 member has d <= r10 <= s9.
__launch_bounds__(256)
__global__ void knn_scan(const float4* __restrict__ pos4, const float4* __restrict__ spos,
                         const int* __restrict__ sidx, const float* __restrict__ s9arr,
                         uint2* __restrict__ segdj) {
    __shared__ float4 cand[SEGSZ];
    int qb = blockIdx.x >> 4, seg = blockIdx.x & 15;
    int tid = threadIdx.x;
    int kq = qb * 256 + tid;
    for (int t = tid; t < SEGSZ; t += 256) cand[t] = pos4[seg * SEGSZ + t];
    float4 q = spos[kq];
    int iorig = sidx[kq];
    float s9 = s9arr[kq];
    __syncthreads();

    DECL_TOP10;
    int jbase = seg * SEGSZ;
    for (int t0 = 0; t0 < SEGSZ; t0 += 8) {
        int jb = jbase + t0;
        float e0, e1, e2, e3, e4, e5, e6, e7;
        { float4 c = cand[t0+0]; float m = c.x*q.x + c.y*q.y + c.z*q.z; e0 = (q.w + c.w) - 2.0f*m; if (jb+0 == iorig) e0 = FLT_MAX; }
        { float4 c = cand[t0+1]; float m = c.x*q.x + c.y*q.y + c.z*q.z; e1 = (q.w + c.w) - 2.0f*m; if (jb+1 == iorig) e1 = FLT_MAX; }
        { float4 c = cand[t0+2]; float m = c.x*q.x + c.y*q.y + c.z*q.z; e2 = (q.w + c.w) - 2.0f*m; if (jb+2 == iorig) e2 = FLT_MAX; }
        { float4 c = cand[t0+3]; float m = c.x*q.x + c.y*q.y + c.z*q.z; e3 = (q.w + c.w) - 2.0f*m; if (jb+3 == iorig) e3 = FLT_MAX; }
        { float4 c = cand[t0+4]; float m = c.x*q.x + c.y*q.y + c.z*q.z; e4 = (q.w + c.w) - 2.0f*m; if (jb+4 == iorig) e4 = FLT_MAX; }
        { float4 c = cand[t0+5]; float m = c.x*q.x + c.y*q.y + c.z*q.z; e5 = (q.w + c.w) - 2.0f*m; if (jb+5 == iorig) e5 = FLT_MAX; }
        { float4 c = cand[t0+6]; float m = c.x*q.x + c.y*q.y + c.z*q.z; e6 = (q.w + c.w) - 2.0f*m; if (jb+6 == iorig) e6 = FLT_MAX; }
        { float4 c = cand[t0+7]; float m = c.x*q.x + c.y*q.y + c.z*q.z; e7 = (q.w + c.w) - 2.0f*m; if (jb+7 == iorig) e7 = FLT_MAX; }
        if (__any(e0 <= s9)) INS10(e0, jb+0);
        if (__any(e1 <= s9)) INS10(e1, jb+1);
        if (__any(e2 <= s9)) INS10(e2, jb+2);
        if (__any(e3 <= s9)) INS10(e3, jb+3);
        if (__any(e4 <= s9)) INS10(e4, jb+4);
        if (__any(e5 <= s9)) INS10(e5, jb+5);
        if (__any(e6 <= s9)) INS10(e6, jb+6);
        if (__any(e7 <= s9)) INS10(e7, jb+7);
    }
    uint2* op = segdj + (seg * NN + kq) * KNN;
    op[0] = make_uint2(__float_as_uint(b0), (unsigned)i0);
    op[1] = make_uint2(__float_as_uint(b1), (unsigned)i1);
    op[2] = make_uint2(__float_as_uint(b2), (unsigned)i2);
    op[3] = make_uint2(__float_as_uint(b3), (unsigned)i3);
    op[4] = make_uint2(__float_as_uint(b4), (unsigned)i4);
    op[5] = make_uint2(__float_as_uint(b5), (unsigned)i5);
    op[6] = make_uint2(__float_as_uint(b6), (unsigned)i6);
    op[7] = make_uint2(__float_as_uint(b7), (unsigned)i7);
    op[8] = make_uint2(__float_as_uint(b8), (unsigned)i8);
    op[9] = make_uint2(__float_as_uint(b9), (unsigned)i9);
}

// ---------------- kNN pass 2: merge 16 sorted lists, early-break --------------
__global__ void knn_merge(const uint2* __restrict__ segdj, const int* __restrict__ sidx,
                          int* __restrict__ nbr) {
    int kq = blockIdx.x * 256 + threadIdx.x;
    DECL_TOP10;
    for (int s = 0; s < NSEG; s++) {       // ascending seg = ascending j on ties
        const uint2* p = segdj + (s * NN + kq) * KNN;
        for (int q = 0; q < KNN; q++) {    // list sorted ascending: break exact
            uint2 v = p[q];
            float d = __uint_as_float(v.x);
            if (d >= b9) break;            // d>=b9 can't insert; rest are >= d
            INS10(d, (int)v.y);
        }
    }
    int* np = nbr + sidx[kq] * KNN;
    np[0] = i0; np[1] = i1; np[2] = i2; np[3] = i3; np[4] = i4;
    np[5] = i5; np[6] = i6; np[7] = i7; np[8] = i8; np[9] = i9;
}

// ---------------- h = lm@emb_w + emb_b ; x = h@rw + rb (R4 verbatim) ----------
__global__ void emb_kernel(const float* __restrict__ lm, const float* __restrict__ ew,
                           const float* __restrict__ eb, const float* __restrict__ rw,
                           const float* __restrict__ rb,
                           float* __restrict__ hdo, unsigned short* __restrict__ hbf,
                           float* __restrict__ xout) {
    __shared__ float s0[4], s1[4], s2[4];
    int i = blockIdx.x, d = threadIdx.x;
    float a0 = lm[i * 3], a1 = lm[i * 3 + 1], a2 = lm[i * 3 + 2];
    float h = eb[d] + a0 * ew[d] + a1 * ew[256 + d] + a2 * ew[512 + d];
    hdo[i * 256 + d] = h;
    hbf[i * 256 + d] = f2bf(h);
    float p0 = h * rw[d * 3], p1 = h * rw[d * 3 + 1], p2 = h * rw[d * 3 + 2];
    for (int off = 32; off; off >>= 1) {
        p0 += __shfl_down(p0, off, 64);
        p1 += __shfl_down(p1, off, 64);
        p2 += __shfl_down(p2, off, 64);
    }
    int lane = d & 63, wid = d >> 6;
    if (lane == 0) { s0[wid] = p0; s1[wid] = p1; s2[wid] = p2; }
    __syncthreads();
    if (d == 0) {
        xout[i * 3 + 0] = s0[0] + s0[1] + s0[2] + s0[3] + rb[0];
        xout[i * 3 + 1] = s1[0] + s1[1] + s1[2] + s1[3] + rb[1];
        xout[i * 3 + 2] = s2[0] + s2[1] + s2[2] + s2[3] + rb[2];
    }
}

// ---------------- hop-1 (R4 verbatim) -----------------------------------------
__global__ void agg_kernel(const unsigned short* __restrict__ src,
                           unsigned short* __restrict__ dst,
                           const int* __restrict__ nbr) {
    int tid = threadIdx.x;
    int wid = tid >> 6, lane = tid & 63;
    int node = blockIdx.x * 4 + wid;
    int d0 = lane * 4;
    float a0 = 0.f, a1 = 0.f, a2 = 0.f, a3 = 0.f;
    const int* nb = nbr + node * KNN;
    for (int q = 0; q < KNN; q++) {
        int j = nb[q];
        uint2 v = *(const uint2*)(src + j * 256 + d0);
        a0 += bf2f((unsigned short)(v.x & 0xffff));
        a1 += bf2f((unsigned short)(v.x >> 16));
        a2 += bf2f((unsigned short)(v.y & 0xffff));
        a3 += bf2f((unsigned short)(v.y >> 16));
    }
    uint2 o;
    o.x = (unsigned)f2bf(a0 * 0.1f) | ((unsigned)f2bf(a1 * 0.1f) << 16);
    o.y = (unsigned)f2bf(a2 * 0.1f) | ((unsigned)f2bf(a3 * 0.1f) << 16);
    *(uint2*)(dst + node * 256 + d0) = o;
}

// ------- fused hop-2 + GEMM + Euler + readout (R4 verbatim) -------------------
__launch_bounds__(256)
__global__ void gemm_step(unsigned short* hbf,
                          const unsigned short* __restrict__ x1,
                          const int* __restrict__ nbr,
                          const unsigned short* __restrict__ Wt,
                          const float* __restrict__ cb,
                          const float* __restrict__ rw, const float* __restrict__ rb,
                          float* hdo, float* __restrict__ yout, float* yfin) {
    __shared__ __align__(16) short Al[32 * 72];
    __shared__ __align__(16) short Bl[256 * 72];
    __shared__ __align__(16) short X2[32 * 264];
    __shared__ float rwl[768];
    __shared__ float cbl[256];
    __shared__ float yred[2][2][4][4][3];

    int tid = threadIdx.x;
    int m0 = blockIdx.x * 32;
    for (int idx = tid; idx < 768; idx += 256) rwl[idx] = rw[idx];
    cbl[tid] = cb[tid];

    {
        int row = tid >> 3, cg = tid & 7;
        const int* nb = nbr + (m0 + row) * KNN;
        float a[32];
#pragma unroll
        for (int e = 0; e < 32; e++) a[e] = 0.f;
        for (int q = 0; q < KNN; q++) {
            int j = nb[q];
            const uint4* p = (const uint4*)(x1 + j * 256 + cg * 32);
#pragma unroll
            for (int u = 0; u < 4; u++) {
                uint4 v = p[u];
                a[u*8+0] += bf2f((unsigned short)(v.x & 0xffff));
                a[u*8+1] += bf2f((unsigned short)(v.x >> 16));
                a[u*8+2] += bf2f((unsigned short)(v.y & 0xffff));
                a[u*8+3] += bf2f((unsigned short)(v.y >> 16));
                a[u*8+4] += bf2f((unsigned short)(v.z & 0xffff));
                a[u*8+5] += bf2f((unsigned short)(v.z >> 16));
                a[u*8+6] += bf2f((unsigned short)(v.w & 0xffff));
                a[u*8+7] += bf2f((unsigned short)(v.w >> 16));
            }
        }
        unsigned short* xp = (unsigned short*)&X2[row * 264 + cg * 32];
#pragma unroll
        for (int u = 0; u < 4; u++) {
            uint2 o;
            o.x = (unsigned)f2bf(a[u*8+0]*0.1f) | ((unsigned)f2bf(a[u*8+1]*0.1f) << 16);
            o.y = (unsigned)f2bf(a[u*8+2]*0.1f) | ((unsigned)f2bf(a[u*8+3]*0.1f) << 16);
            uint2 o2;
            o2.x = (unsigned)f2bf(a[u*8+4]*0.1f) | ((unsigned)f2bf(a[u*8+5]*0.1f) << 16);
            o2.y = (unsigned)f2bf(a[u*8+6]*0.1f) | ((unsigned)f2bf(a[u*8+7]*0.1f) << 16);
            *(uint2*)(xp + u * 8) = o;
            *(uint2*)(xp + u * 8 + 4) = o2;
        }
    }

    f4v acc[8];
    for (int f = 0; f < 8; f++) acc[f] = (f4v){0.f, 0.f, 0.f, 0.f};

    int w = tid >> 6, lane = tid & 63;
    int rowgrp = w & 1, nhalf = w >> 1;
    int quad = lane >> 4, l15 = lane & 15;

    for (int kc = 0; kc < 12; kc++) {
        int kb = kc * 64;
        int klocal = kb & 255;
        if (kc < 8) {
            const unsigned short* asrc = (kb < 256) ? hbf : x1;
            int row = tid >> 3, c8 = (tid & 7) * 8;
            uint4 v = *(const uint4*)(asrc + (m0 + row) * 256 + klocal + c8);
            *(uint4*)(&Al[row * 72 + c8]) = v;
        }
        {
            const unsigned short* bsrc = Wt + (kb >> 8) * 65536;
            int c8 = (tid & 7) * 8, rbase = tid >> 3;
            for (int r2 = 0; r2 < 8; r2++) {
                int n = r2 * 32 + rbase;
                uint4 v = *(const uint4*)(bsrc + n * 256 + klocal + c8);
                *(uint4*)(&Bl[n * 72 + c8]) = v;
            }
        }
        __syncthreads();
        for (int ks = 0; ks < 2; ks++) {
            s8v a;
            if (kc < 8)
                a = *(const s8v*)(&Al[(rowgrp * 16 + l15) * 72 + ks * 32 + quad * 8]);
            else
                a = *(const s8v*)(&X2[(rowgrp * 16 + l15) * 264 + klocal + ks * 32 + quad * 8]);
            for (int f = 0; f < 8; f++) {
                int n = nhalf * 128 + f * 16 + l15;
                s8v b = *(const s8v*)(&Bl[n * 72 + ks * 32 + quad * 8]);
                acc[f] = __builtin_amdgcn_mfma_f32_16x16x32_bf16(a, b, acc[f], 0, 0, 0);
            }
        }
        __syncthreads();
    }

    float py[4][3] = {};
    for (int f = 0; f < 8; f++) {
        int col = nhalf * 128 + f * 16 + l15;
        float cbv = cbl[col];
        float rw0 = rwl[col * 3], rw1 = rwl[col * 3 + 1], rw2 = rwl[col * 3 + 2];
        for (int r = 0; r < 4; r++) {
            int grow = m0 + rowgrp * 16 + quad * 4 + r;
            float cval = acc[f][r] + cbv;
            float hn = hdo[grow * 256 + col] + EPSC * tanhf(cval);
            hdo[grow * 256 + col] = hn;
            hbf[grow * 256 + col] = f2bf(hn);
            py[r][0] += hn * rw0; py[r][1] += hn * rw1; py[r][2] += hn * rw2;
        }
    }
    for (int off = 1; off < 16; off <<= 1)
        for (int r = 0; r < 4; r++)
            for (int j = 0; j < 3; j++)
                py[r][j] += __shfl_xor(py[r][j], off, 64);
    if (l15 == 0)
        for (int r = 0; r < 4; r++)
            for (int j = 0; j < 3; j++)
                yred[rowgrp][nhalf][quad][r][j] = py[r][j];
    __syncthreads();
    if (nhalf == 0 && l15 == 0) {
        for (int r = 0; r < 4; r++) {
            int grow = m0 + rowgrp * 16 + quad * 4 + r;
            for (int j = 0; j < 3; j++) {
                float yv = yred[rowgrp][0][quad][r][j] + yred[rowgrp][1][quad][r][j] + rb[j];
                yout[grow * 3 + j] = yv;
                if (yfin) yfin[grow * 3 + j] = yv;
            }
        }
    }
}

extern "C" void kernel_launch(void* const* d_in, const int* in_sizes, int n_in,
                              void* d_out, int out_size, void* d_ws, size_t ws_size,
                              hipStream_t stream) {
    const float* lm = (const float*)d_in[0];
    const float* ew = (const float*)d_in[1];
    const float* eb = (const float*)d_in[2];
    const float* rw = (const float*)d_in[3];
    const float* rb = (const float*)d_in[4];
    const float* cw = (const float*)d_in[5];
    const float* cb = (const float*)d_in[6];

    float* out = (float*)d_out;
    float* y_out = out;
    float* h_out = out + 24576;
    float* x_out = out + 24576 + 2097152;
    float* lp_out = x_out + 24576;

    char* ws = (char*)d_ws;
    int* nbr = (int*)ws;            ws += NN * KNN * sizeof(int);
    float4* pos4 = (float4*)ws;     ws += NN * sizeof(float4);
    int* counts = (int*)ws;         ws += NCELL * sizeof(int);
    int* starts = (int*)ws;         ws += (NCELL + 1) * sizeof(int);
    int* cellof = (int*)ws;         ws += NN * sizeof(int);
    int* slotof = (int*)ws;         ws += NN * sizeof(int);
    float4* spos = (float4*)ws;     ws += NN * sizeof(float4);
    int* sidx = (int*)ws;           ws += NN * sizeof(int);
    float* s9arr = (float*)ws;      ws += NN * sizeof(float);
    // union: segdj (kNN scratch, 10.5 MB) aliases {hbf, x1, Wt} (sim, 8.4 MB)
    char* uni = ws;
    uint2* segdj = (uint2*)uni;
    unsigned short* hbf = (unsigned short*)uni;
    unsigned short* x1  = hbf + NN * DH;
    unsigned short* Wt  = x1 + NN * DH;

    prep_pos<<<NN / 256, 256, 0, stream>>>(lm, pos4);
    grid_zero<<<NCELL / 256, 256, 0, stream>>>(counts);
    grid_bin<<<NN / 256, 256, 0, stream>>>(lm, counts, cellof, slotof);
    grid_prefix<<<1, 256, 0, stream>>>(counts, starts);
    grid_scatter<<<NN / 256, 256, 0, stream>>>(lm, starts, cellof, slotof, spos, sidx);
    s9_seed<<<NN / 64, 64, 0, stream>>>(spos, s9arr);
    knn_scan<<<32 * NSEG, 256, 0, stream>>>(pos4, spos, sidx, s9arr, segdj);
    knn_merge<<<NN / 256, 256, 0, stream>>>(segdj, sidx, nbr);
    prep_wt<<<768, 256, 0, stream>>>(cw, Wt);
    emb_kernel<<<NN, 256, 0, stream>>>(lm, ew, eb, rw, rb, h_out, hbf, x_out);
    for (int t = 0; t < TSTEPS; t++) {
        agg_kernel<<<NN / 4, 256, 0, stream>>>(hbf, x1, nbr);
        gemm_step<<<NN / 32, 256, 0, stream>>>(hbf, x1, nbr, Wt, cb, rw, rb, h_out,
                                               lp_out + t * 24576,
                                               (t == TSTEPS - 1) ? y_out : nullptr);
    }
}